// Round 1
// 587.724 us; speedup vs baseline: 1.0268x; 1.0268x over previous
//
#include <hip/hip_runtime.h>

// Problem constants (from reference setup_inputs)
#define BB 256
#define CC 2048
#define KK 18
#define HWW 192   // 24*8
#define CH_PER_THREAD 2
#define BLOCK 256

// out[b, 0:C]   = pool_global_feat[b, :]
// out[b, C:2C]  = max_k ( sum_hw masks[b,k,hw] * feat[b,c,hw] ) / HW
//
// Geometry note: total threads = B*C/CH is invariant to block size, so the
// ONLY way to raise occupancy past 2 waves/SIMD is lowering CH_PER_THREAD.
// CH=2 -> 1024 blocks -> 4 blocks/CU -> 16 waves/CU (4 waves/SIMD).
// LDS mask-broadcast instr count doubles (~23 us on LDS pipe) but stays
// under the ~65 us HBM floor; latency hiding on the VMEM pipe doubles.
__global__ __launch_bounds__(BLOCK, 4)
void pgfa_pose_guided_kernel(const float* __restrict__ feat,
                             const float* __restrict__ masks,
                             const float* __restrict__ pgf,
                             float* __restrict__ out) {
    __shared__ float sm[KK][HWW];   // 13.8 KB; 4 blocks/CU -> 55 KB of 160 KB

    const int tid = threadIdx.x;
    const int b   = blockIdx.y;

    // Stage masks[b] into LDS, coalesced float4 loads: 864 float4s / 256 threads
    {
        const float4* m4 = (const float4*)(masks + (size_t)b * KK * HWW);
        float4* s4 = (float4*)(&sm[0][0]);
        for (int i = tid; i < (KK * HWW) / 4; i += BLOCK) s4[i] = m4[i];
    }
    __syncthreads();

    const int c0 = blockIdx.x * (BLOCK * CH_PER_THREAD) + tid * CH_PER_THREAD;
    const float* frow = feat + ((size_t)b * CC + (size_t)c0) * HWW;

    float acc[KK][CH_PER_THREAD];
    #pragma unroll
    for (int k = 0; k < KK; ++k)
        #pragma unroll
        for (int j = 0; j < CH_PER_THREAD; ++j) acc[k][j] = 0.0f;

    // Stream feat rows; 48 float4 steps over hw. unroll 2 keeps 4 loads in
    // flight per thread (x 16 waves/CU = plenty of in-flight bytes).
    #pragma unroll 2
    for (int hw4 = 0; hw4 < HWW / 4; ++hw4) {
        float4 f[CH_PER_THREAD];
        #pragma unroll
        for (int j = 0; j < CH_PER_THREAD; ++j)
            f[j] = ((const float4*)(frow + j * HWW))[hw4];

        #pragma unroll
        for (int k = 0; k < KK; ++k) {
            const float4 m = ((const float4*)(&sm[k][0]))[hw4];  // wave-uniform broadcast
            #pragma unroll
            for (int j = 0; j < CH_PER_THREAD; ++j) {
                acc[k][j] += m.x * f[j].x;
                acc[k][j] += m.y * f[j].y;
                acc[k][j] += m.z * f[j].z;
                acc[k][j] += m.w * f[j].w;
            }
        }
    }

    // max over k, then scale once (max is monotone under positive scaling)
    const float inv_hw = 1.0f / (float)HWW;
    float r[CH_PER_THREAD];
    #pragma unroll
    for (int j = 0; j < CH_PER_THREAD; ++j) {
        float v = acc[0][j];
        #pragma unroll
        for (int k = 1; k < KK; ++k) v = fmaxf(v, acc[k][j]);
        r[j] = v * inv_hw;
    }

    // out layout [B, 2C]: first C = pool_global_feat copy, second C = pg_max
    float* orow = out + (size_t)b * (2 * CC);
    const float2 pg2 = ((const float2*)(pgf + (size_t)b * CC))[c0 / 2];
    float2 res; res.x = r[0]; res.y = r[1];
    ((float2*)orow)[c0 / 2] = pg2;
    ((float2*)(orow + CC))[c0 / 2] = res;
}

extern "C" void kernel_launch(void* const* d_in, const int* in_sizes, int n_in,
                              void* d_out, int out_size, void* d_ws, size_t ws_size,
                              hipStream_t stream) {
    const float* feat  = (const float*)d_in[0];  // [B, C, H, W] fp32
    const float* masks = (const float*)d_in[1];  // [B, K, H, W] fp32
    const float* pgf   = (const float*)d_in[2];  // [B, C] fp32
    float* out = (float*)d_out;                  // [B, 2C] fp32

    dim3 grid(CC / (BLOCK * CH_PER_THREAD), BB);  // (4, 256) = 1024 blocks
    pgfa_pose_guided_kernel<<<grid, BLOCK, 0, stream>>>(feat, masks, pgf, out);
}